// Round 11
// baseline (474.633 us; speedup 1.0000x reference)
//
#include <hip/hip_runtime.h>
#include <hip/hip_bf16.h>
#include <stdint.h>

// ComplexDFT256: out(65536x512) = X(65536x512) @ W^T, W = [[cos,-sin],[sin,cos]].
// R5 per-wave structure, but 256-thread blocks (4 waves) covering j in TWO
// passes -> up to 6-8 co-resident blocks/CU (vs ~1.5 with 512-thread blocks).
// Occupancy is the one untested axis; all schedule variants pinned at ~70us.

typedef __attribute__((ext_vector_type(8))) short bf16x8;
typedef __attribute__((ext_vector_type(4))) float f32x4;

#define KDIM 512
#define NDIM 512
#define BM 64

__device__ __forceinline__ ushort f2bf(float f) {
  union { float f; uint32_t u; } v; v.f = f;
  uint32_t r = (v.u + 0x7fffu + ((v.u >> 16) & 1u)) >> 16;  // RNE
  return (ushort)r;
}

// Fragment-ordered W: Wf[8*g .. 8*g+7], g = k5*2048 + nt*64 + lane, holds
// W[j = nt*16 + (lane&15)][k = k5*32 + (lane>>4)*8 + e]  (e = 0..7)
__global__ __launch_bounds__(512) void build_w_kernel(const float* __restrict__ cosk,
                                                      const float* __restrict__ sink,
                                                      ushort* __restrict__ Wf) {
  int g = blockIdx.x * 512 + threadIdx.x;   // 0..32767
  int lane = g & 63;
  int nt = (g >> 6) & 31;
  int j = nt * 16 + (lane & 15);
  int kbase = (g >> 11) * 32 + (lane >> 4) * 8;
  bf16x8 w8;
#pragma unroll
  for (int e = 0; e < 8; ++e) {
    int k = kbase + e;
    float v;
    if (j < 256) {
      v = (k < 256) ? cosk[(j << 8) + k] : -sink[(j << 8) + (k - 256)];
    } else {
      int jj = j - 256;
      v = (k < 256) ? sink[(jj << 8) + k] : cosk[(jj << 8) + (k - 256)];
    }
    w8[e] = (short)f2bf(v);
  }
  *reinterpret_cast<bf16x8*>(Wf + (size_t)g * 8) = w8;
}

__device__ __forceinline__ bf16x8 cvt8(f32x4 a, f32x4 b) {
  bf16x8 w8;
  w8[0] = (short)f2bf(a[0]); w8[1] = (short)f2bf(a[1]);
  w8[2] = (short)f2bf(a[2]); w8[3] = (short)f2bf(a[3]);
  w8[4] = (short)f2bf(b[0]); w8[5] = (short)f2bf(b[1]);
  w8[6] = (short)f2bf(b[2]); w8[7] = (short)f2bf(b[3]);
  return w8;
}

// Block = 64 batch rows x 256 threads (4 waves). Wave w, pass p computes the
// 64-j strip at j-base (p*4+w)*64 x all 64 batch rows. K-loop identical to R5:
// per-step double-buffered LDS X tile + fragment-ordered W streams from L2.
__global__ __launch_bounds__(256, 6) void dft_gemm_kernel(const float* __restrict__ A,
                                                          const ushort* __restrict__ Wf,
                                                          float* __restrict__ out) {
  __shared__ ushort As[2][BM * 64];   // 2 x 8 KB

  const int tid  = threadIdx.x;
  const int lane = tid & 63;
  const int wid  = tid >> 6;            // 0..3
  const int m0   = blockIdx.x * BM;     // batch-row base

  // staging: 256 threads, each 16 floats (four f32x4) of one row per K-tile
  const int srow  = tid >> 2;           // 0..63
  const int skq   = (tid & 3) * 16;     // float offset within 64-wide subtile
  const float* ap = A + (size_t)(m0 + srow) * KDIM + skq;
  const int slot0 = (tid & 3) * 2;      // 8-elem slot index (0,2,4,6)
  const int eA = srow * 64 + (((slot0)     ^ (srow & 7)) << 3);
  const int eB = srow * 64 + (((slot0 + 1) ^ (srow & 7)) << 3);

  const int lrow = lane & 15;
  const int lk8  = (lane >> 4) * 8;

  for (int p = 0; p < 2; ++p) {
    const int c0 = (p * 4 + wid) * 64;   // j base for this wave, this pass
    // W frag base: ((t*2+kk)*32 + nt)*512 + lane*8; nt = c0/16 + mi
    const ushort* wp = Wf + (size_t)(c0 >> 4) * 512 + lane * 8;

    f32x4 acc[4][4] = {};   // [mi = j-tile][ni = batch-tile]

    // ---- prologue: stage subtile 0 -> As[0]; subtile 1 loads in flight ----
    {
      f32x4 s0 = *reinterpret_cast<const f32x4*>(ap);
      f32x4 s1 = *reinterpret_cast<const f32x4*>(ap + 4);
      f32x4 s2 = *reinterpret_cast<const f32x4*>(ap + 8);
      f32x4 s3 = *reinterpret_cast<const f32x4*>(ap + 12);
      *reinterpret_cast<bf16x8*>(&As[0][eA]) = cvt8(s0, s1);
      *reinterpret_cast<bf16x8*>(&As[0][eB]) = cvt8(s2, s3);
    }
    f32x4 p0 = *reinterpret_cast<const f32x4*>(ap + 64);
    f32x4 p1 = *reinterpret_cast<const f32x4*>(ap + 68);
    f32x4 p2 = *reinterpret_cast<const f32x4*>(ap + 72);
    f32x4 p3 = *reinterpret_cast<const f32x4*>(ap + 76);
    asm volatile("s_waitcnt lgkmcnt(0)" ::: "memory");
    __builtin_amdgcn_s_barrier();

#pragma unroll
    for (int t = 0; t < 8; ++t) {
      // 1) write next X subtile to the other buffer
      if (t < 7) {
        *reinterpret_cast<bf16x8*>(&As[(t + 1) & 1][eA]) = cvt8(p0, p1);
        *reinterpret_cast<bf16x8*>(&As[(t + 1) & 1][eB]) = cvt8(p2, p3);
      }

      // 2) all 8 W frag loads for this K-step (coalesced 1KB L2 streams)
      bf16x8 wfr[2][4];
#pragma unroll
      for (int kk = 0; kk < 2; ++kk)
#pragma unroll
        for (int mi = 0; mi < 4; ++mi)
          wfr[kk][mi] = *reinterpret_cast<const bf16x8*>(
              wp + (size_t)((t * 2 + kk) * 32 + mi) * 512);

      // 3) issue X subtile t+2
      if (t < 6) {
        const float* apn = ap + (t + 2) * 64;
        p0 = *reinterpret_cast<const f32x4*>(apn);
        p1 = *reinterpret_cast<const f32x4*>(apn + 4);
        p2 = *reinterpret_cast<const f32x4*>(apn + 8);
        p3 = *reinterpret_cast<const f32x4*>(apn + 12);
      }

      // 4) LDS reads + MFMAs
#pragma unroll
      for (int kk = 0; kk < 2; ++kk) {
        bf16x8 xfr[4];
#pragma unroll
        for (int ni = 0; ni < 4; ++ni) {
          int row = ni * 16 + lrow;
          int idx = (row << 6) + ((kk * 32 + lk8) ^ ((lrow & 7) << 3));
          xfr[ni] = *reinterpret_cast<const bf16x8*>(&As[t & 1][idx]);
        }
#pragma unroll
        for (int mi = 0; mi < 4; ++mi)
#pragma unroll
          for (int ni = 0; ni < 4; ++ni)
            acc[mi][ni] = __builtin_amdgcn_mfma_f32_16x16x32_bf16(
                wfr[kk][mi], xfr[ni], acc[mi][ni], 0, 0, 0);
      }

      // 5) single barrier per K-step; vmem stays in flight
      if (t < 7) {
        asm volatile("s_waitcnt lgkmcnt(0)" ::: "memory");
        __builtin_amdgcn_s_barrier();
      }
    }

    // ---- epilogue: lane holds 4 contiguous j's -> f32x4 stores ----
    const int jbase = c0 + (lane >> 4) * 4;
#pragma unroll
    for (int ni = 0; ni < 4; ++ni) {
      size_t rowb = (size_t)(m0 + ni * 16 + lrow) * NDIM;
#pragma unroll
      for (int mi = 0; mi < 4; ++mi)
        *reinterpret_cast<f32x4*>(out + rowb + jbase + mi * 16) = acc[mi][ni];
    }

    // rendezvous before pass 2 re-stages As[0] (all pass-1 LDS reads done)
    if (p == 0) {
      asm volatile("s_waitcnt lgkmcnt(0)" ::: "memory");
      __builtin_amdgcn_s_barrier();
    }
  }
}

extern "C" void kernel_launch(void* const* d_in, const int* in_sizes, int n_in,
                              void* d_out, int out_size, void* d_ws, size_t ws_size,
                              hipStream_t stream) {
  const float* x    = (const float*)d_in[0];   // (65536, 2, 256) fp32
  const float* cosk = (const float*)d_in[1];   // (256, 256) fp32
  const float* sink = (const float*)d_in[2];   // (256, 256) fp32
  float* out = (float*)d_out;                  // (65536, 512, 1) fp32
  ushort* Wf = (ushort*)d_ws;                  // 512 KB fragment-ordered W

  build_w_kernel<<<64, 512, 0, stream>>>(cosk, sink, Wf);
  dft_gemm_kernel<<<65536 / BM, 256, 0, stream>>>(x, Wf, out);
}

// Round 13
// 274.074 us; speedup vs baseline: 1.7318x; 1.7318x over previous
//
#include <hip/hip_runtime.h>
#include <hip/hip_bf16.h>
#include <stdint.h>

// ComplexDFT256: out(65536x512) = X(65536x512) @ W^T, W = [[cos,-sin],[sin,cos]].
// MLP design: NO LDS, NO barriers, fully independent waves. Wave = 32j x 64b.
// X loaded global->reg 3-deep (24 outstanding loads/wave); W fragment-ordered
// L2 streams 3-deep; cvt via v_cvt_pk_bf16_f32. XCD swizzle shares X via L2
// across the 4 j-quadrant blocks of each batch strip.

typedef __attribute__((ext_vector_type(8))) short bf16x8;
typedef __attribute__((ext_vector_type(4))) float f32x4;

#define KDIM 512
#define NDIM 512

__device__ __forceinline__ ushort f2bf(float f) {
  union { float f; uint32_t u; } v; v.f = f;
  uint32_t r = (v.u + 0x7fffu + ((v.u >> 16) & 1u)) >> 16;  // RNE
  return (ushort)r;
}

// Fragment-ordered W: Wf[8*g .. 8*g+7], g = k5*2048 + nt*64 + lane, holds
// W[j = nt*16 + (lane&15)][k = k5*32 + (lane>>4)*8 + e]  (e = 0..7), k5 = 0..15
__global__ __launch_bounds__(512) void build_w_kernel(const float* __restrict__ cosk,
                                                      const float* __restrict__ sink,
                                                      ushort* __restrict__ Wf) {
  int g = blockIdx.x * 512 + threadIdx.x;   // 0..32767
  int lane = g & 63;
  int nt = (g >> 6) & 31;
  int j = nt * 16 + (lane & 15);
  int kbase = (g >> 11) * 32 + (lane >> 4) * 8;
  bf16x8 w8;
#pragma unroll
  for (int e = 0; e < 8; ++e) {
    int k = kbase + e;
    float v;
    if (j < 256) {
      v = (k < 256) ? cosk[(j << 8) + k] : -sink[(j << 8) + (k - 256)];
    } else {
      int jj = j - 256;
      v = (k < 256) ? sink[(jj << 8) + k] : cosk[(jj << 8) + (k - 256)];
    }
    w8[e] = (short)f2bf(v);
  }
  *reinterpret_cast<bf16x8*>(Wf + (size_t)g * 8) = w8;
}

__device__ __forceinline__ bf16x8 cvt8(f32x4 a, f32x4 b) {
  uint32_t r0, r1, r2, r3;
  asm("v_cvt_pk_bf16_f32 %0, %1, %2" : "=v"(r0) : "v"(a[0]), "v"(a[1]));
  asm("v_cvt_pk_bf16_f32 %0, %1, %2" : "=v"(r1) : "v"(a[2]), "v"(a[3]));
  asm("v_cvt_pk_bf16_f32 %0, %1, %2" : "=v"(r2) : "v"(b[0]), "v"(b[1]));
  asm("v_cvt_pk_bf16_f32 %0, %1, %2" : "=v"(r3) : "v"(b[2]), "v"(b[3]));
  union { uint32_t u[4]; bf16x8 v; } u;
  u.u[0] = r0; u.u[1] = r1; u.u[2] = r2; u.u[3] = r3;
  return u.v;
}

// Grid 4096 x 256 threads. Block (xcd = bid&7, i = bid>>3):
//   strip s = (i>>2)*8 + xcd (64 batch rows), j-quadrant jb = i&3 (128 j).
// Wave wid owns j in [jb*128 + wid*32, +32). 16 K-steps of 32. No LDS/barriers.
__global__ __launch_bounds__(256, 2) void dft_gemm_kernel(const float* __restrict__ A,
                                                          const ushort* __restrict__ Wf,
                                                          float* __restrict__ out) {
  const int tid  = threadIdx.x;
  const int lane = tid & 63;
  const int wid  = tid >> 6;            // 0..3
  const int bid  = blockIdx.x;
  const int xcd  = bid & 7;
  const int i    = bid >> 3;
  const int s    = (i >> 2) * 8 + xcd;  // batch strip 0..1023
  const int jb   = i & 3;               // j quadrant
  const int m0   = s * 64;
  const int c0   = jb * 128 + wid * 32;
  const int lrow = lane & 15;
  const int g16  = lane >> 4;           // 0..3

  // X: lane reads rows m0 + ni*16 + lrow, 8 consecutive floats at col t*32 + g16*8
  const float* xp0 = A + (size_t)(m0 + lrow) * KDIM + g16 * 8;
  // W frag (jt, k5): wp + (k5*32 + jt)*512
  const ushort* wp = Wf + (size_t)(c0 >> 4) * 512 + lane * 8;

  f32x4 acc[2][4] = {};    // [jt][ni]
  f32x4 xq[3][8];          // 3-deep X pipeline: [slot][ni*2 + half]
  bf16x8 wq[3][2];         // 3-deep W pipeline: [slot][jt]

  // ---- prologue: fill pipeline with steps 0,1,2 ----
#pragma unroll
  for (int p = 0; p < 3; ++p) {
#pragma unroll
    for (int ni = 0; ni < 4; ++ni) {
      const float* q = xp0 + (size_t)ni * 16 * KDIM + p * 32;
      xq[p][2 * ni]     = *reinterpret_cast<const f32x4*>(q);
      xq[p][2 * ni + 1] = *reinterpret_cast<const f32x4*>(q + 4);
    }
    wq[p][0] = *reinterpret_cast<const bf16x8*>(wp + (size_t)(p * 32)     * 512);
    wq[p][1] = *reinterpret_cast<const bf16x8*>(wp + (size_t)(p * 32 + 1) * 512);
  }

#pragma unroll
  for (int t = 0; t < 16; ++t) {
    const int sl = t % 3;   // compile-time after full unroll

    // convert step t (compiler inserts counted vmcnt wait for xq[sl] only)
    bf16x8 xf[4];
#pragma unroll
    for (int ni = 0; ni < 4; ++ni)
      xf[ni] = cvt8(xq[sl][2 * ni], xq[sl][2 * ni + 1]);

    // reissue X step t+3 into the freed slot (distance ~3 iterations)
    if (t < 13) {
#pragma unroll
      for (int ni = 0; ni < 4; ++ni) {
        const float* q = xp0 + (size_t)ni * 16 * KDIM + (t + 3) * 32;
        xq[sl][2 * ni]     = *reinterpret_cast<const f32x4*>(q);
        xq[sl][2 * ni + 1] = *reinterpret_cast<const f32x4*>(q + 4);
      }
    }

    // MFMAs for step t (W issued 3 steps ago)
#pragma unroll
    for (int ni = 0; ni < 4; ++ni) {
      acc[0][ni] = __builtin_amdgcn_mfma_f32_16x16x32_bf16(
          wq[sl][0], xf[ni], acc[0][ni], 0, 0, 0);
      acc[1][ni] = __builtin_amdgcn_mfma_f32_16x16x32_bf16(
          wq[sl][1], xf[ni], acc[1][ni], 0, 0, 0);
    }

    // reissue W step t+3
    if (t < 13) {
      wq[sl][0] = *reinterpret_cast<const bf16x8*>(wp + (size_t)((t + 3) * 32)     * 512);
      wq[sl][1] = *reinterpret_cast<const bf16x8*>(wp + (size_t)((t + 3) * 32 + 1) * 512);
    }
  }

  // ---- epilogue: lane holds 4 contiguous j's per acc -> f32x4 stores ----
  const int jbase = c0 + g16 * 4;
#pragma unroll
  for (int ni = 0; ni < 4; ++ni) {
    size_t rowb = (size_t)(m0 + ni * 16 + lrow) * NDIM;
    *reinterpret_cast<f32x4*>(out + rowb + jbase)      = acc[0][ni];
    *reinterpret_cast<f32x4*>(out + rowb + jbase + 16) = acc[1][ni];
  }
}

extern "C" void kernel_launch(void* const* d_in, const int* in_sizes, int n_in,
                              void* d_out, int out_size, void* d_ws, size_t ws_size,
                              hipStream_t stream) {
  const float* x    = (const float*)d_in[0];   // (65536, 2, 256) fp32
  const float* cosk = (const float*)d_in[1];   // (256, 256) fp32
  const float* sink = (const float*)d_in[2];   // (256, 256) fp32
  float* out = (float*)d_out;                  // (65536, 512, 1) fp32
  ushort* Wf = (ushort*)d_ws;                  // 512 KB fragment-ordered W

  build_w_kernel<<<64, 512, 0, stream>>>(cosk, sink, Wf);
  dft_gemm_kernel<<<4096, 256, 0, stream>>>(x, Wf, out);
}

// Round 14
// 259.159 us; speedup vs baseline: 1.8314x; 1.0576x over previous
//
#include <hip/hip_runtime.h>
#include <hip/hip_bf16.h>
#include <stdint.h>

// ComplexDFT256: out(65536x512) = X(65536x512) @ W^T, W = [[cos,-sin],[sin,cos]].
// MLP design v2: no LDS, no block barriers, independent waves (32j x 64b each).
// 2-deep FORCED register pipeline: sched_barrier(0) fences + counted
// s_waitcnt vmcnt(10) keep one full K-step's loads (8 X + 2 W) in flight
// per wave at all times. R13 failed because the scheduler sank the loads
// (VGPR=44); the fences make that illegal.

typedef __attribute__((ext_vector_type(8))) short bf16x8;
typedef __attribute__((ext_vector_type(4))) float f32x4;

#define KDIM 512
#define NDIM 512

__device__ __forceinline__ ushort f2bf(float f) {
  union { float f; uint32_t u; } v; v.f = f;
  uint32_t r = (v.u + 0x7fffu + ((v.u >> 16) & 1u)) >> 16;  // RNE
  return (ushort)r;
}

// Fragment-ordered W: Wf[8*g .. 8*g+7], g = k5*2048 + nt*64 + lane, holds
// W[j = nt*16 + (lane&15)][k = k5*32 + (lane>>4)*8 + e]  (e = 0..7), k5 = 0..15
__global__ __launch_bounds__(512) void build_w_kernel(const float* __restrict__ cosk,
                                                      const float* __restrict__ sink,
                                                      ushort* __restrict__ Wf) {
  int g = blockIdx.x * 512 + threadIdx.x;   // 0..32767
  int lane = g & 63;
  int nt = (g >> 6) & 31;
  int j = nt * 16 + (lane & 15);
  int kbase = (g >> 11) * 32 + (lane >> 4) * 8;
  bf16x8 w8;
#pragma unroll
  for (int e = 0; e < 8; ++e) {
    int k = kbase + e;
    float v;
    if (j < 256) {
      v = (k < 256) ? cosk[(j << 8) + k] : -sink[(j << 8) + (k - 256)];
    } else {
      int jj = j - 256;
      v = (k < 256) ? sink[(jj << 8) + k] : cosk[(jj << 8) + (k - 256)];
    }
    w8[e] = (short)f2bf(v);
  }
  *reinterpret_cast<bf16x8*>(Wf + (size_t)g * 8) = w8;
}

__device__ __forceinline__ bf16x8 cvt8(f32x4 a, f32x4 b) {
  uint32_t r0, r1, r2, r3;
  asm("v_cvt_pk_bf16_f32 %0, %1, %2" : "=v"(r0) : "v"(a[0]), "v"(a[1]));
  asm("v_cvt_pk_bf16_f32 %0, %1, %2" : "=v"(r1) : "v"(a[2]), "v"(a[3]));
  asm("v_cvt_pk_bf16_f32 %0, %1, %2" : "=v"(r2) : "v"(b[0]), "v"(b[1]));
  asm("v_cvt_pk_bf16_f32 %0, %1, %2" : "=v"(r3) : "v"(b[2]), "v"(b[3]));
  union { uint32_t u[4]; bf16x8 v; } u;
  u.u[0] = r0; u.u[1] = r1; u.u[2] = r2; u.u[3] = r3;
  return u.v;
}

// Grid 4096 x 256 threads. Block (xcd = bid&7, i = bid>>3):
//   strip s = (i>>2)*8 + xcd (64 batch rows), j-quadrant jb = i&3 (128 j).
// Wave wid owns j in [jb*128 + wid*32, +32). 16 K-steps of 32.
__global__ __launch_bounds__(256) void dft_gemm_kernel(const float* __restrict__ A,
                                                       const ushort* __restrict__ Wf,
                                                       float* __restrict__ out) {
  const int tid  = threadIdx.x;
  const int lane = tid & 63;
  const int wid  = tid >> 6;            // 0..3
  const int bid  = blockIdx.x;
  const int xcd  = bid & 7;
  const int i    = bid >> 3;
  const int s    = (i >> 2) * 8 + xcd;  // batch strip 0..1023
  const int jb   = i & 3;               // j quadrant
  const int m0   = s * 64;
  const int c0   = jb * 128 + wid * 32;
  const int lrow = lane & 15;
  const int g16  = lane >> 4;           // 0..3

  // X: lane reads rows m0 + ni*16 + lrow, 8 floats at col t*32 + g16*8
  const float* xp0 = A + (size_t)(m0 + lrow) * KDIM + g16 * 8;
  // W frag (jt, k5) at wp + (k5*32 + jt)*512
  const ushort* wp = Wf + (size_t)(c0 >> 4) * 512 + lane * 8;

  f32x4 acc[2][4] = {};    // [jt][ni]
  f32x4 xq[2][8];          // 2-deep X pipeline
  bf16x8 wq[2][2];         // 2-deep W pipeline

  // ---- prologue: issue step-0 loads into buffer 0 ----
#pragma unroll
  for (int ni = 0; ni < 4; ++ni) {
    const float* q = xp0 + (size_t)ni * 16 * KDIM;
    xq[0][2 * ni]     = *reinterpret_cast<const f32x4*>(q);
    xq[0][2 * ni + 1] = *reinterpret_cast<const f32x4*>(q + 4);
  }
  wq[0][0] = *reinterpret_cast<const bf16x8*>(wp);
  wq[0][1] = *reinterpret_cast<const bf16x8*>(wp + (size_t)512);

#pragma unroll
  for (int t = 0; t < 16; ++t) {
    const int cb = t & 1;       // compute buffer (static after unroll)
    const int nb = cb ^ 1;      // load buffer

    // A) issue the 10 loads for step t+1
    if (t < 15) {
#pragma unroll
      for (int ni = 0; ni < 4; ++ni) {
        const float* q = xp0 + (size_t)ni * 16 * KDIM + (t + 1) * 32;
        xq[nb][2 * ni]     = *reinterpret_cast<const f32x4*>(q);
        xq[nb][2 * ni + 1] = *reinterpret_cast<const f32x4*>(q + 4);
      }
      wq[nb][0] = *reinterpret_cast<const bf16x8*>(wp + (size_t)((t + 1) * 32)     * 512);
      wq[nb][1] = *reinterpret_cast<const bf16x8*>(wp + (size_t)((t + 1) * 32 + 1) * 512);
    }
    __builtin_amdgcn_sched_barrier(0);

    // B) counted wait: step t complete, step t+1's 10 loads stay in flight
    if (t < 15) asm volatile("s_waitcnt vmcnt(10)" ::: "memory");
    else        asm volatile("s_waitcnt vmcnt(0)"  ::: "memory");
    __builtin_amdgcn_sched_barrier(0);

    // C) cvt + MFMA on step t
    bf16x8 xf[4];
#pragma unroll
    for (int ni = 0; ni < 4; ++ni)
      xf[ni] = cvt8(xq[cb][2 * ni], xq[cb][2 * ni + 1]);
#pragma unroll
    for (int ni = 0; ni < 4; ++ni) {
      acc[0][ni] = __builtin_amdgcn_mfma_f32_16x16x32_bf16(
          wq[cb][0], xf[ni], acc[0][ni], 0, 0, 0);
      acc[1][ni] = __builtin_amdgcn_mfma_f32_16x16x32_bf16(
          wq[cb][1], xf[ni], acc[1][ni], 0, 0, 0);
    }
  }

  // ---- epilogue: lane holds 4 contiguous j's per acc -> f32x4 stores ----
  const int jbase = c0 + g16 * 4;
#pragma unroll
  for (int ni = 0; ni < 4; ++ni) {
    size_t rowb = (size_t)(m0 + ni * 16 + lrow) * NDIM;
    *reinterpret_cast<f32x4*>(out + rowb + jbase)      = acc[0][ni];
    *reinterpret_cast<f32x4*>(out + rowb + jbase + 16) = acc[1][ni];
  }
}

extern "C" void kernel_launch(void* const* d_in, const int* in_sizes, int n_in,
                              void* d_out, int out_size, void* d_ws, size_t ws_size,
                              hipStream_t stream) {
  const float* x    = (const float*)d_in[0];   // (65536, 2, 256) fp32
  const float* cosk = (const float*)d_in[1];   // (256, 256) fp32
  const float* sink = (const float*)d_in[2];   // (256, 256) fp32
  float* out = (float*)d_out;                  // (65536, 512, 1) fp32
  ushort* Wf = (ushort*)d_ws;                  // 512 KB fragment-ordered W

  build_w_kernel<<<64, 512, 0, stream>>>(cosk, sink, Wf);
  dft_gemm_kernel<<<4096, 256, 0, stream>>>(x, Wf, out);
}

// Round 16
// 183.744 us; speedup vs baseline: 2.5831x; 1.4104x over previous
//
#include <hip/hip_runtime.h>
#include <hip/hip_bf16.h>
#include <stdint.h>

// ComplexDFT256: out(65536x512) = X(65536x512) @ W^T, W = [[cos,-sin],[sin,cos]].
// W-STATIONARY design: block = 512 batch x 64 j. W strip (64KB, fragment-
// ordered) loaded into LDS ONCE via global_load_lds (ALL 4096 chunks, 8/thread;
// R15 bug: only 1024 were staged). K-loop's only global stream is X,
// burst-issued one compute phase ahead. Per-wave math/swizzles from R5.

typedef __attribute__((ext_vector_type(8))) short bf16x8;
typedef __attribute__((ext_vector_type(4))) float f32x4;

#define KDIM 512
#define NDIM 512

__device__ __forceinline__ ushort f2bf(float f) {
  union { float f; uint32_t u; } v; v.f = f;
  uint32_t r = (v.u + 0x7fffu + ((v.u >> 16) & 1u)) >> 16;  // RNE
  return (ushort)r;
}

// Fragment-ordered W: Wf[8*g .. 8*g+7], g = k5*2048 + nt*64 + lane, holds
// W[j = nt*16 + (lane&15)][k = k5*32 + (lane>>4)*8 + e]  (e = 0..7), k5 = 0..15
__global__ __launch_bounds__(512) void build_w_kernel(const float* __restrict__ cosk,
                                                      const float* __restrict__ sink,
                                                      ushort* __restrict__ Wf) {
  int g = blockIdx.x * 512 + threadIdx.x;   // 0..32767
  int lane = g & 63;
  int nt = (g >> 6) & 31;
  int j = nt * 16 + (lane & 15);
  int kbase = (g >> 11) * 32 + (lane >> 4) * 8;
  bf16x8 w8;
#pragma unroll
  for (int e = 0; e < 8; ++e) {
    int k = kbase + e;
    float v;
    if (j < 256) {
      v = (k < 256) ? cosk[(j << 8) + k] : -sink[(j << 8) + (k - 256)];
    } else {
      int jj = j - 256;
      v = (k < 256) ? sink[(jj << 8) + k] : cosk[(jj << 8) + (k - 256)];
    }
    w8[e] = (short)f2bf(v);
  }
  *reinterpret_cast<bf16x8*>(Wf + (size_t)g * 8) = w8;
}

__device__ __forceinline__ bf16x8 cvt8(f32x4 a, f32x4 b) {
  bf16x8 w8;
  w8[0] = (short)f2bf(a[0]); w8[1] = (short)f2bf(a[1]);
  w8[2] = (short)f2bf(a[2]); w8[3] = (short)f2bf(a[3]);
  w8[4] = (short)f2bf(b[0]); w8[5] = (short)f2bf(b[1]);
  w8[6] = (short)f2bf(b[2]); w8[7] = (short)f2bf(b[3]);
  return w8;
}

__device__ __forceinline__ void gload_lds16(const ushort* g, ushort* l) {
  __builtin_amdgcn_global_load_lds(
      (__attribute__((address_space(1))) const void*)g,
      (__attribute__((address_space(3))) void*)l, 16, 0, 0);
}

// Grid 1024. p: xcd = p&7, r = p>>3, q = r&7 (j-block), s = (r>>3)*8 + xcd
// (batch strip). All 8 j-blocks of a strip land on one XCD -> X L2-shared.
// Block: 512 threads, 8 waves; wave wid owns batch rows [wid*64, +64) x all
// 64 j of the block. 8 K-steps of 64.
__global__ __launch_bounds__(512) void dft_gemm_kernel(const float* __restrict__ A,
                                                       const ushort* __restrict__ Wf,
                                                       float* __restrict__ out) {
  __shared__ ushort Ws[16 * 256 * 8];   // 64 KB fragment-ordered W strip
  __shared__ ushort Xs[512 * 64];       // 64 KB X tile (bf16, XOR-swizzled)

  const int tid  = threadIdx.x;
  const int lane = tid & 63;
  const int wid  = tid >> 6;              // 0..7
  const int p    = blockIdx.x;
  const int xcd  = p & 7;
  const int r    = p >> 3;
  const int q    = r & 7;                 // j-block (64 j's)
  const int s    = (r >> 3) * 8 + xcd;    // batch strip (512 rows)
  const int m0   = s * 512;
  const int lrow = lane & 15;
  const int lk8  = (lane >> 4) * 8;

  // ---- prologue: W strip -> LDS via global_load_lds, ALL 4096 16B chunks ----
  // chunk c = rr*512 + wid*64 + lane: k5 = c>>8 (wave-uniform), off = c&255;
  // global src = Wf + (k5*2048 + q*256 + off)*8 (per-lane, contiguous 1KB/wave);
  // LDS dest = wave-uniform base, HW adds lane*16.
#pragma unroll
  for (int rr = 0; rr < 8; ++rr) {
    int cb  = rr * 512 + wid * 64;        // wave-uniform chunk base
    int c   = cb + lane;
    int k5  = c >> 8;
    int off = c & 255;
    gload_lds16(Wf + ((size_t)k5 * 2048 + q * 256 + off) * 8,
                Ws + (size_t)cb * 8);
  }

  // X staging: thread owns block-local row tid, 64 floats per K-step.
  const float* ap = A + (size_t)(m0 + tid) * KDIM;
  f32x4 xr[16];
#pragma unroll
  for (int i = 0; i < 16; ++i)
    xr[i] = *reinterpret_cast<const f32x4*>(ap + i * 4);

  // write X tile 0 (R5 swizzle: 16B slot s8 -> s8 ^ (row&7))
#pragma unroll
  for (int s8 = 0; s8 < 8; ++s8) {
    int idx = (tid << 6) + ((s8 ^ (tid & 7)) << 3);
    *reinterpret_cast<bf16x8*>(&Xs[idx]) = cvt8(xr[2 * s8], xr[2 * s8 + 1]);
  }
  asm volatile("s_waitcnt vmcnt(0) lgkmcnt(0)" ::: "memory");  // W + X0 in LDS
  __builtin_amdgcn_s_barrier();

  f32x4 acc[4][4] = {};   // [mi = j-tile][ni = batch-tile]

#pragma unroll
  for (int t = 0; t < 8; ++t) {
    // A) burst-issue X(t+1): 16 loads, land during compute below
    if (t < 7) {
      const float* apn = ap + (t + 1) * 64;
#pragma unroll
      for (int i = 0; i < 16; ++i)
        xr[i] = *reinterpret_cast<const f32x4*>(apn + i * 4);
    }

    // B) compute step t: W frags and X frags from LDS
#pragma unroll
    for (int kk = 0; kk < 2; ++kk) {
      bf16x8 wfr[4], xfr[4];
#pragma unroll
      for (int mi = 0; mi < 4; ++mi)
        wfr[mi] = *reinterpret_cast<const bf16x8*>(
            &Ws[(size_t)(((t * 2 + kk) * 256) + mi * 64 + lane) * 8]);
#pragma unroll
      for (int ni = 0; ni < 4; ++ni) {
        int row = wid * 64 + ni * 16 + lrow;   // block-local 0..511
        int idx = (row << 6) + ((kk * 32 + lk8) ^ ((row & 7) << 3));
        xfr[ni] = *reinterpret_cast<const bf16x8*>(&Xs[idx]);
      }
#pragma unroll
      for (int mi = 0; mi < 4; ++mi)
#pragma unroll
        for (int ni = 0; ni < 4; ++ni)
          acc[mi][ni] = __builtin_amdgcn_mfma_f32_16x16x32_bf16(
              wfr[mi], xfr[ni], acc[mi][ni], 0, 0, 0);
    }

    // C) reads(t) done -> barrier -> overwrite tile with X(t+1) -> barrier
    if (t < 7) {
      asm volatile("s_waitcnt lgkmcnt(0)" ::: "memory");
      __builtin_amdgcn_s_barrier();
#pragma unroll
      for (int s8 = 0; s8 < 8; ++s8) {
        int idx = (tid << 6) + ((s8 ^ (tid & 7)) << 3);
        *reinterpret_cast<bf16x8*>(&Xs[idx]) = cvt8(xr[2 * s8], xr[2 * s8 + 1]);
      }
      asm volatile("s_waitcnt lgkmcnt(0)" ::: "memory");
      __builtin_amdgcn_s_barrier();
    }
  }

  // ---- epilogue: lane holds 4 contiguous j's -> f32x4 stores (R5 layout) ----
  const int jbase = q * 64 + (lane >> 4) * 4;
#pragma unroll
  for (int ni = 0; ni < 4; ++ni) {
    size_t rowb = (size_t)(m0 + wid * 64 + ni * 16 + lrow) * NDIM;
#pragma unroll
    for (int mi = 0; mi < 4; ++mi)
      *reinterpret_cast<f32x4*>(out + rowb + jbase + mi * 16) = acc[mi][ni];
  }
}

extern "C" void kernel_launch(void* const* d_in, const int* in_sizes, int n_in,
                              void* d_out, int out_size, void* d_ws, size_t ws_size,
                              hipStream_t stream) {
  const float* x    = (const float*)d_in[0];   // (65536, 2, 256) fp32
  const float* cosk = (const float*)d_in[1];   // (256, 256) fp32
  const float* sink = (const float*)d_in[2];   // (256, 256) fp32
  float* out = (float*)d_out;                  // (65536, 512, 1) fp32
  ushort* Wf = (ushort*)d_ws;                  // 512 KB fragment-ordered W

  build_w_kernel<<<64, 512, 0, stream>>>(cosk, sink, Wf);
  dft_gemm_kernel<<<1024, 512, 0, stream>>>(x, Wf, out);
}